// Round 7
// baseline (317.696 us; speedup 1.0000x reference)
//
#include <hip/hip_runtime.h>
#include <hip/hip_bf16.h>

// ---------------------------------------------------------------------------
// QuantizedLinear: out[M,N] = (x[M,K] @ (Wq[N,K]*s[N,1]).T) + b[N]
// INT8 path (R6-validated, absmax 7.0): w -> i8 exact, x -> i8 per-row quant,
// mfma_i32_16x16x64_i8, epilogue acc*sx[m]*s[n]+b.
// Round 7: m97-regime GEMM. R6's model fit showed FULL serialization of LDS
// (768 cyc) + MFMA (640 cyc) per tile: 8-wave blocks x2/CU phase-lock at
// barriers. Now 128x128 tile, 4 waves (2Mx2N, per-wave 64x64), ring-3 LDS
// 48 KiB -> 3 blocks/CU (12 waves from 3 INDEPENDENT blocks stagger), and
// exactly ONE {vmcnt(4); s_barrier} per K-tile (2nd barrier proven redundant:
// readers' lgkm-drain precedes their barrier arrival, ordering slot WAR).
// ---------------------------------------------------------------------------

typedef __attribute__((ext_vector_type(4))) int   i32x4;
typedef __attribute__((ext_vector_type(4))) float f32x4;
typedef __attribute__((ext_vector_type(4))) unsigned int u32x4;

// ---- w: fp32 (integer-valued) -> i8, exact ---------------------------------
__device__ static inline unsigned int pack4(int q0, int q1, int q2, int q3) {
    return (unsigned)(q0 & 255) | ((unsigned)(q1 & 255) << 8) |
           ((unsigned)(q2 & 255) << 16) | ((unsigned)(q3 & 255) << 24);
}

__global__ void w_to_i8(const float* __restrict__ in,
                        u32x4* __restrict__ out, long n16) {
    const long stride = (long)gridDim.x * blockDim.x;
    for (long i = (long)blockIdx.x * blockDim.x + threadIdx.x; i < n16; i += stride) {
        const f32x4* p = reinterpret_cast<const f32x4*>(in) + i * 4;
        u32x4 o;
#pragma unroll
        for (int v = 0; v < 4; ++v) {
            f32x4 f = p[v];
            o[v] = pack4(__float2int_rn(f[0]), __float2int_rn(f[1]),
                         __float2int_rn(f[2]), __float2int_rn(f[3]));
        }
        out[i] = o;
    }
}

// ---- x: per-row absmax quant to i8; sx[row] = rowmax/127 -------------------
__global__ void x_quant_i8(const float* __restrict__ x,
                           unsigned int* __restrict__ xq,
                           float* __restrict__ sx, int K) {
    const int row = blockIdx.x;
    const int tid = threadIdx.x;
    const float* xr = x + (size_t)row * K;
    float m = 0.f;
    for (int b = tid * 16; b < K; b += blockDim.x * 16) {
        const f32x4* p = (const f32x4*)(xr + b);
#pragma unroll
        for (int v = 0; v < 4; ++v) {
            f32x4 f = p[v];
            m = fmaxf(m, fmaxf(fmaxf(fabsf(f[0]), fabsf(f[1])),
                               fmaxf(fabsf(f[2]), fabsf(f[3]))));
        }
    }
#pragma unroll
    for (int off = 32; off; off >>= 1) m = fmaxf(m, __shfl_xor(m, off));
    __shared__ float red[8];
    if ((tid & 63) == 0) red[tid >> 6] = m;
    __syncthreads();
    const int nw = blockDim.x >> 6;
    m = red[0];
    for (int i = 1; i < nw; ++i) m = fmaxf(m, red[i]);
    const float inv = (m > 0.f) ? 127.0f / m : 0.f;
    if (tid == 0) sx[row] = m * (1.0f / 127.0f);
    for (int b = tid * 16; b < K; b += blockDim.x * 16) {
        const f32x4* p = (const f32x4*)(xr + b);
        u32x4 o;
#pragma unroll
        for (int v = 0; v < 4; ++v) {
            f32x4 f = p[v];
            int q0 = min(127, max(-127, __float2int_rn(f[0] * inv)));
            int q1 = min(127, max(-127, __float2int_rn(f[1] * inv)));
            int q2 = min(127, max(-127, __float2int_rn(f[2] * inv)));
            int q3 = min(127, max(-127, __float2int_rn(f[3] * inv)));
            o[v] = pack4(q0, q1, q2, q3);
        }
        *reinterpret_cast<u32x4*>((char*)xq + (size_t)row * K + b) = o;
    }
}

// ---------------------------------------------------------------------------
// i8 GEMM. Tile 128x128, BK=64. 256 thr = 4 waves (2M x 2N), per-wave 64x64.
// LDS 48 KiB: A slots sl*8K (128x64 i8), B slots 24K + sl*8K. Ring-3, stage
// lead-2 (4 gloads/thread/tile), vmcnt(4) + s_barrier once per tile.
// Swizzle: 64B rows, 16B phys chunk = logical ^ ((row>>1)&3); staging
// pre-swizzles the GLOBAL source, LDS dest linear (rule #21). 0 conflicts
// measured with identical geometry in R6.
// ---------------------------------------------------------------------------

#define GLOAD16(src, dst) __builtin_amdgcn_global_load_lds( \
    (const __attribute__((address_space(1))) void*)(src),   \
    (__attribute__((address_space(3))) void*)(dst), 16, 0, 0)

#define FENCE() asm volatile("" ::: "memory")
#define BAR()  do { FENCE(); __builtin_amdgcn_s_barrier(); FENCE(); } while (0)
#define WAIT_VM(n) asm volatile("s_waitcnt vmcnt(" #n ")" ::: "memory")

__global__ __launch_bounds__(256, 3)
void qlinear_gemm_i8(const char* __restrict__ A,   // [M,K] i8
                     const char* __restrict__ B,   // [N,K] i8
                     const float* __restrict__ sx, // [M] row scales of x
                     const float* __restrict__ scales,  // [N]
                     const float* __restrict__ bias,    // [N]
                     float* __restrict__ C,             // [M,N] f32
                     int M, int N, int K, int nbx) {
    __shared__ __align__(128) char smem[49152];

    const int tid  = threadIdx.x;
    const int lane = tid & 63;
    const int wid  = tid >> 6;
    const int mslab = (wid >> 1) * 64;   // 2 M-slabs
    const int nslab = (wid & 1) * 64;    // 2 N-slabs

    // T1: bijective XCD swizzle (m204); bcol-fastest (A-panel L2-resident)
    const int nwg = gridDim.x;
    const int q = nwg >> 3, r = nwg & 7;
    const int xcd = blockIdx.x & 7, boff_ = blockIdx.x >> 3;
    const int swz = (xcd < r ? xcd * (q + 1) : r * (q + 1) + (xcd - r) * q) + boff_;
    const int bcol = swz % nbx;
    const int brow = swz / nbx;

    const char* Ag = A + (size_t)brow * 128 * K;
    const char* Bg = B + (size_t)bcol * 128 * K;

    // ---- staging: 512 chunks per 8K slot; chunk c -> row c>>2, phys c&3.
    // LDS dest linear (c*16); global source k-chunk = (c&3) ^ ((row>>1)&3).
    const int c0 = tid, c1 = tid + 256;
    const int r0 = c0 >> 2, p0 = c0 & 3;
    const int r1 = c1 >> 2, p1 = c1 & 3;
    const size_t g0 = (size_t)r0 * K + ((p0 ^ ((r0 >> 1) & 3)) << 4);
    const size_t g1 = (size_t)r1 * K + ((p1 ^ ((r1 >> 1) & 3)) << 4);

    auto stageT = [&](int sl, int t) {
        const size_t ko = (size_t)t * 64;
        char* base = smem + sl * 8192;
        GLOAD16(Ag + g0 + ko, base + c0 * 16);
        GLOAD16(Ag + g1 + ko, base + c1 * 16);
        GLOAD16(Bg + g0 + ko, base + 24576 + c0 * 16);
        GLOAD16(Bg + g1 + ko, base + 24576 + c1 * 16);
    };

    // ---- reads: frag row = slab + f*16 + (lane&15); phys chunk =
    // (lane>>4) ^ ((lane>>1)&3).
    const int cph  = ((lane >> 4) ^ ((lane >> 1) & 3)) << 4;
    const int aoff = (mslab + (lane & 15)) * 64 + cph;
    const int boff = (nslab + (lane & 15)) * 64 + cph;

    i32x4 acc[4][4] = {};
    i32x4 af[4], bf[4];

    auto rdAB = [&](int sl) {
        const char* pa = smem + sl * 8192 + aoff;
#pragma unroll
        for (int mi = 0; mi < 4; ++mi) af[mi] = *(const i32x4*)(pa + mi * 1024);
        const char* pb = smem + 24576 + sl * 8192 + boff;
#pragma unroll
        for (int ni = 0; ni < 4; ++ni) bf[ni] = *(const i32x4*)(pb + ni * 1024);
    };
    auto mfma16 = [&]() {
        __builtin_amdgcn_s_setprio(1);
#pragma unroll
        for (int mi = 0; mi < 4; ++mi)
#pragma unroll
            for (int ni = 0; ni < 4; ++ni)
                acc[mi][ni] = __builtin_amdgcn_mfma_i32_16x16x64_i8(
                    af[mi], bf[ni], acc[mi][ni], 0, 0, 0);
        __builtin_amdgcn_s_setprio(0);
    };

    const int NT = K / 64;   // >= 3 guaranteed by dispatch

    // ---- prologue: stage tiles 0,1 (8 gloads); tile0 landed after vm(4) ----
    stageT(0, 0); stageT(1, 1);
    WAIT_VM(4); BAR();

    // ---- main loop: ONE {vmcnt(4); barrier} per tile ----
    // Correctness: reader's mfma lgkm-drain precedes its barrier arrival, so
    // after BAR(t) every wave's reads of slot t%3 are complete -> staging
    // slot (t+3)%3 at iter t+1 is WAR-safe. vm(4)+BAR publishes tile t+1.
    int sl = 0;
    for (int t = 0; t < NT - 2; ++t) {
        int sl2 = sl + 2; if (sl2 >= 3) sl2 -= 3;
        stageT(sl2, t + 2);
        rdAB(sl);
        mfma16();
        WAIT_VM(4);        // retire tile t+1's 4 gloads; keep t+2's in flight
        BAR();
        sl = (sl == 2) ? 0 : sl + 1;
    }
    // t = NT-2
    rdAB(sl);
    mfma16();
    WAIT_VM(0);            // last tile landed
    BAR();
    sl = (sl == 2) ? 0 : sl + 1;
    // t = NT-1
    rdAB(sl);
    mfma16();

    // ---- epilogue: C/D layout col=lane&15, row=(lane>>4)*4+j ----
    const int lc  = lane & 15;
    const int lr4 = (lane >> 4) * 4;
    float sarr[4], barr[4];
#pragma unroll
    for (int ni = 0; ni < 4; ++ni) {
        const int n = bcol * 128 + nslab + ni * 16 + lc;
        sarr[ni] = scales[n];
        barr[ni] = bias[n];
    }
#pragma unroll
    for (int mi = 0; mi < 4; ++mi) {
        const int mb = brow * 128 + mslab + mi * 16 + lr4;
        const f32x4 sxv = *(const f32x4*)&sx[mb];
#pragma unroll
        for (int j = 0; j < 4; ++j) {
            const size_t rowoff = (size_t)(mb + j) * N;
            const float sm = sxv[j];
#pragma unroll
            for (int ni = 0; ni < 4; ++ni) {
                const int n = bcol * 128 + nslab + ni * 16 + lc;
                C[rowoff + n] = fmaf((float)acc[mi][ni][j], sm * sarr[ni], barr[ni]);
            }
        }
    }
}

// ---- Fallback: plain fp32 tiled GEMM, correctness insurance ----------------
__global__ void qlinear_fallback(const float* __restrict__ A,
                                 const float* __restrict__ B,
                                 const float* __restrict__ scales,
                                 const float* __restrict__ bias,
                                 float* __restrict__ C, int M, int N, int K) {
    __shared__ float As[16][17], Bs[16][17];
    const int tx = threadIdx.x, ty = threadIdx.y;
    const int row = blockIdx.y * 16 + ty;
    const int col = blockIdx.x * 16 + tx;
    float acc = 0.f;
    for (int k0 = 0; k0 < K; k0 += 16) {
        As[ty][tx] = A[(long)row * K + k0 + tx];
        Bs[ty][tx] = B[(long)(blockIdx.x * 16 + ty) * K + k0 + tx];
        __syncthreads();
#pragma unroll
        for (int kk = 0; kk < 16; ++kk) acc += As[ty][kk] * Bs[tx][kk];
        __syncthreads();
    }
    C[(long)row * N + col] = fmaf(acc, scales[col], bias[col]);
}

extern "C" void kernel_launch(void* const* d_in, const int* in_sizes, int n_in,
                              void* d_out, int out_size, void* d_ws, size_t ws_size,
                              hipStream_t stream) {
    const float* x      = (const float*)d_in[0];
    const float* w      = (const float*)d_in[1];
    const float* scales = (const float*)d_in[2];
    const float* bias   = (const float*)d_in[3];
    float* out = (float*)d_out;

    const int N = in_sizes[2];                  // 11008
    const int K = (int)((long)in_sizes[1] / N); // 4096
    const int M = (int)((long)in_sizes[0] / K); // 4096

    const size_t need = (size_t)M * K + (size_t)N * K + (size_t)M * 4;
    const bool ok = (ws_size >= need) && (M % 128) == 0 && (N % 128) == 0 &&
                    (K % 64) == 0 && (K / 64) >= 3 && (K % 16) == 0;

    if (ok) {
        char* xq = (char*)d_ws;
        char* wq = xq + (size_t)M * K;
        float* sxbuf = (float*)(wq + (size_t)N * K);

        x_quant_i8<<<M, 256, 0, stream>>>(x, (unsigned int*)xq, sxbuf, K);
        w_to_i8<<<2048, 256, 0, stream>>>(w, (u32x4*)wq, (long)N * K / 16);

        const int nbx = N / 128;
        const int nwg = (M / 128) * nbx;
        qlinear_gemm_i8<<<nwg, 256, 0, stream>>>(xq, wq, sxbuf, scales, bias,
                                                 out, M, N, K, nbx);
    } else {
        dim3 grid(N / 16, M / 16), blk(16, 16);
        qlinear_fallback<<<grid, blk, 0, stream>>>(x, w, scales, bias, out, M, N, K);
    }
}